// Round 9
// baseline (189.969 us; speedup 1.0000x reference)
//
#include <hip/hip_runtime.h>
#include <stdint.h>

// Problem constants
#define B_    8
#define CIN   512
#define NPIX  16384
#define CK    256
#define KCTX  64
#define CV    256

typedef _Float16 f16;
typedef _Float16 f16x4 __attribute__((ext_vector_type(4)));
typedef _Float16 f16x8 __attribute__((ext_vector_type(8)));
typedef float    f32x4 __attribute__((ext_vector_type(4)));

#define LOG2E 1.44269504f

// ws layout (bytes), total 1 MB. Both tables in exact MFMA fragment order.
// WQK: A-frag for sim.  byte = ((((s*4+mi)*2+kk)*4+g)*16+ln)*16 + 2*j
//      holds Wqk^T(c,m)*1/16 with c = 64s+32kk+8g+j, m = 16mi+ln
// WPV: B-frag for out.  byte = (((ct*2+kk)*4+g)*16+lnc)*16 + 2*j
//      holds Wpv(c,m) with c = 16ct+lnc, m = 16*(2kk+(j>>2))+4g+(j&3)
#define WQK_OFF 0           // 512 KB : [b][64 KB]
#define WPV_OFF 524288      // 512 KB : [b][64 KB]

__device__ __forceinline__ void gl_lds16(const void* g, void* l) {
    __builtin_amdgcn_global_load_lds(
        (const __attribute__((address_space(1))) uint32_t*)g,
        (__attribute__((address_space(3))) uint32_t*)l, 16, 0, 0);
}

// ---------------------------------------------------------------------------
// prep: grid (4, B), 1024 threads, 64 KB LDS.  (unchanged from rounds 6-8)
// ---------------------------------------------------------------------------
__global__ __launch_bounds__(1024) void prep(const float* __restrict__ ctx,
                                             const float* __restrict__ Wk,
                                             const float* __restrict__ Wv,
                                             const float* __restrict__ Wq,
                                             const float* __restrict__ Wp,
                                             char* __restrict__ ws) {
    __shared__ char lds[65536];
    char* ctx_t = lds;              // 32 KB
    char* kv_s  = lds + 32768;      // 32 KB

    const int p = blockIdx.x;
    const int b = blockIdx.y;
    const int path = p >> 1, h = p & 1;
    const int t = threadIdx.x;
    const int w = t >> 6, l = t & 63, g = l >> 4, ln = l & 15;

    // ---- stage ctx transposed: ctx_t[m][c] f16 swz ----
    {
        const int m4 = (t & 15) * 4, c4 = (t >> 4) * 4;
        const float* cp = ctx + (size_t)b * (CV * KCTX) + (size_t)c4 * KCTX + m4;
        f32x4 xr[4];
        #pragma unroll
        for (int i = 0; i < 4; ++i) xr[i] = *(const f32x4*)(cp + (size_t)i * KCTX);
        #pragma unroll
        for (int j = 0; j < 4; ++j) {
            f16x4 v4; v4[0] = (f16)xr[0][j]; v4[1] = (f16)xr[1][j]; v4[2] = (f16)xr[2][j]; v4[3] = (f16)xr[3][j];
            int m = m4 + j;
            *(f16x4*)(ctx_t + m * 512 + 16 * (((c4 >> 3) & 31) ^ (m & 7)) + 2 * (c4 & 7)) = v4;
        }
    }
    __syncthreads();

    // ---- kv GEMM: D[row][m] = (path? Wv : Wk) * ctx, K=256 ----
    {
        const float* W = path ? Wv : Wk;
        const int rbase = 64 * (w >> 2);
        const int mm = 16 * (w & 3) + ln;
        f32x4 acc[4] = {};
        for (int ks = 0; ks < 8; ++ks) {
            f16x8 bf = *(const f16x8*)(ctx_t + mm * 512 + 16 * ((4 * ks + g) ^ (mm & 7)));
            #pragma unroll
            for (int mi = 0; mi < 4; ++mi) {
                int row = rbase + 16 * mi + ln;
                const float* wp0 = W + (size_t)row * CV + 32 * ks + 8 * g;
                f32x4 lo = *(const f32x4*)wp0, hi = *(const f32x4*)(wp0 + 4);
                f16x8 af;
                #pragma unroll
                for (int j = 0; j < 4; ++j) { af[j] = (f16)lo[j]; af[4 + j] = (f16)hi[j]; }
                acc[mi] = __builtin_amdgcn_mfma_f32_16x16x32_f16(af, bf, acc[mi], 0, 0, 0);
            }
        }
        #pragma unroll
        for (int mi = 0; mi < 4; ++mi)
            #pragma unroll
            for (int r = 0; r < 4; ++r) {
                int row = rbase + 16 * mi + 4 * g + r;
                *(f16*)(kv_s + mm * 512 + 16 * ((((row >> 3) & 31)) ^ (mm & 7)) + 2 * (row & 7)) = (f16)acc[mi][r];
            }
    }
    __syncthreads();

    if (path == 0) {
        // ---- Wqk^T[c][m] = sum_kk Wq[kk][c] k[kk][m]; A gathered from global ----
        f32x4 acc2[4] = {};
        const int cA = 256 * h + 16 * w + ln;
        const float* qcol = Wq + cA;
        for (int ks = 0; ks < 8; ++ks) {
            f16x8 af;
            #pragma unroll
            for (int j = 0; j < 8; ++j)
                af[j] = (f16)qcol[(size_t)(32 * ks + 8 * g + j) * CIN];
            #pragma unroll
            for (int ni = 0; ni < 4; ++ni) {
                int m2 = 16 * ni + ln;
                f16x8 bf = *(const f16x8*)(kv_s + m2 * 512 + 16 * ((4 * ks + g) ^ (m2 & 7)));
                acc2[ni] = __builtin_amdgcn_mfma_f32_16x16x32_f16(af, bf, acc2[ni], 0, 0, 0);
            }
        }
        char* dst = ws + WQK_OFF + b * 65536;
        #pragma unroll
        for (int ni = 0; ni < 4; ++ni)
            #pragma unroll
            for (int r = 0; r < 4; ++r) {
                int c = 256 * h + 16 * w + 4 * g + r;     // k-dim index of sim GEMM
                int s  = c >> 6, kk = (c >> 5) & 1, gk = (c >> 3) & 3, j = c & 7;
                int byte = ((((s * 4 + ni) * 2 + kk) * 4 + gk) * 16 + ln) * 16 + 2 * j;
                *(f16*)(dst + byte) = (f16)(acc2[ni][r] * 0.0625f);   // fold scale 1/16
            }
    } else {
        // ---- Wpv[c][m] = sum_v Wp[c][v] v[v][m]; A direct from global ----
        f32x4 acc2[4] = {};
        const int cA = 256 * h + 16 * w + ln;
        for (int ks = 0; ks < 8; ++ks) {
            const float* pp = Wp + (size_t)cA * CV + 32 * ks + 8 * g;
            f32x4 lo = *(const f32x4*)pp, hi = *(const f32x4*)(pp + 4);
            f16x8 af;
            #pragma unroll
            for (int j = 0; j < 4; ++j) { af[j] = (f16)lo[j]; af[4 + j] = (f16)hi[j]; }
            #pragma unroll
            for (int ni = 0; ni < 4; ++ni) {
                int m2 = 16 * ni + ln;
                f16x8 bf = *(const f16x8*)(kv_s + m2 * 512 + 16 * ((4 * ks + g) ^ (m2 & 7)));
                acc2[ni] = __builtin_amdgcn_mfma_f32_16x16x32_f16(af, bf, acc2[ni], 0, 0, 0);
            }
        }
        char* dst = ws + WPV_OFF + b * 65536;
        #pragma unroll
        for (int ni = 0; ni < 4; ++ni) {
            const int kkm = ni >> 1;
            const int gm  = ln >> 2;
            const int jm  = 4 * (ni & 1) + (ln & 3);
            #pragma unroll
            for (int r = 0; r < 4; ++r) {
                int c = 256 * h + 16 * w + 4 * g + r;     // output-channel index
                int ct = c >> 4, lnc = c & 15;
                int byte = (((ct * 2 + kkm) * 4 + gm) * 16 + lnc) * 16 + 2 * jm;
                *(f16*)(dst + byte) = (f16)acc2[ni][r];
            }
        }
    }
}

// ---------------------------------------------------------------------------
// fused: 1024 threads = 16 waves, ONE block per CU (128 KB dynamic LDS).
//  - Wqk table (64 KB, frag-ordered) staged once via global_load_lds; sim
//    A-frags become ds_read_b128 (L2 latency off the critical path).
//  - Each wave owns 32 px + a private 4 KB single-buffer x-transpose slice;
//    zero barriers after the one staging __syncthreads.
//  - out: attn in regs (A-frag) x Wpv streamed from L2 (B-frag, amortized
//    over 2 n-tiles), f32x4 stores.
// ---------------------------------------------------------------------------
__global__ __launch_bounds__(1024) void fused(const float* __restrict__ x,
                                              const char* __restrict__ ws,
                                              float* __restrict__ out) {
    extern __shared__ char lds[];              // 128 KB dynamic
    char* wqk_l = lds;                         // 64 KB: Wqk frag table
    const int b = blockIdx.y;
    const int t = threadIdx.x;
    const int w = t >> 6, l = t & 63, g = l >> 4, ln = l & 15;
    const int nb = blockIdx.x * 512 + 32 * w;
    char* wl = lds + 65536 + w * 4096;         // wave-private x buffer (4 KB)

    const char* wqk_g = ws + WQK_OFF + b * 65536;
    const char* wpv   = ws + WPV_OFF + b * 65536;
    const float* xb = x + (size_t)b * CIN * NPIX + nb;

    // stage Wqk table -> LDS (byte copy; table already frag-ordered)
    #pragma unroll
    for (int r = 0; r < 4; ++r) {
        int ch = t + 1024 * r;
        gl_lds16(wqk_g + ch * 16, wqk_l + ch * 16);
    }

    // staging decomposition: lane l: cg = (l>>3) + 8u  (16 c-groups of 4),
    // n4 = 4*(l&7) (32 px / 8 n-groups). Load i covers c = 4*cg + i.
    const int n4 = 4 * (l & 7);
    const int cg0 = (l >> 3);

    f32x4 xr[2][4];

#define STAGE_LOAD(S)                                                          \
    {                                                                          \
        _Pragma("unroll")                                                      \
        for (int u = 0; u < 2; ++u) {                                          \
            const float* xp = xb + (size_t)(64 * (S) + 4 * (cg0 + 8 * u)) * NPIX + n4; \
            _Pragma("unroll")                                                  \
            for (int i = 0; i < 4; ++i)                                        \
                xr[u][i] = *(const f32x4*)(xp + (size_t)i * NPIX);             \
        }                                                                      \
    }

#define STAGE_WRITE(BUF)                                                       \
    {                                                                          \
        _Pragma("unroll")                                                      \
        for (int u = 0; u < 2; ++u) {                                          \
            int cg = cg0 + 8 * u;                                              \
            _Pragma("unroll")                                                  \
            for (int j = 0; j < 4; ++j) {                                      \
                f16x4 v4;                                                      \
                v4[0] = (f16)xr[u][0][j]; v4[1] = (f16)xr[u][1][j];            \
                v4[2] = (f16)xr[u][2][j]; v4[3] = (f16)xr[u][3][j];            \
                int nl = n4 + j;                                               \
                int fn = (nl ^ (nl >> 3)) & 7;                                 \
                *(f16x4*)((BUF) + nl * 128 + 16 * ((cg >> 1) ^ fn) + 8 * (cg & 1)) = v4; \
            }                                                                  \
        }                                                                      \
    }

    // prologue: x chunk 0 -> regs -> private LDS
    STAGE_LOAD(0);
    STAGE_WRITE(wl);
    __syncthreads();   // Wqk table staged (drains vmcnt; x(0) writes visible)

    // ---- sim: 8 c-chunks of 64; only VMEM in loop = 8 x-loads ----
    f32x4 accs[2][4] = {};   // [nt][mi]
    #pragma unroll
    for (int s = 0; s < 8; ++s) {
        if (s < 7) STAGE_LOAD(s + 1);
        #pragma unroll
        for (int kk = 0; kk < 2; ++kk) {
            f16x8 bf[2];
            #pragma unroll
            for (int nt = 0; nt < 2; ++nt) {
                int nl = 16 * nt + ln;
                int fn = (nl ^ (nl >> 3)) & 7;
                bf[nt] = *(const f16x8*)(wl + nl * 128 + 16 * ((4 * kk + g) ^ fn));
            }
            #pragma unroll
            for (int mi = 0; mi < 4; ++mi) {
                f16x8 af = *(const f16x8*)(wqk_l + ((((s * 4 + mi) * 2 + kk) * 4 + g) * 16 + ln) * 16);
                accs[0][mi] = __builtin_amdgcn_mfma_f32_16x16x32_f16(af, bf[0], accs[0][mi], 0, 0, 0);
                accs[1][mi] = __builtin_amdgcn_mfma_f32_16x16x32_f16(af, bf[1], accs[1][mi], 0, 0, 0);
            }
        }
        if (s < 7) STAGE_WRITE(wl);   // in-order DS per wave: reads of s precede
    }

    // ---- softmax over m (64) per n-tile, in-register ----
    f16x8 afr[2][2];   // [nt][kk]
    #pragma unroll
    for (int nt = 0; nt < 2; ++nt) {
        float mx = accs[nt][0][0];
        #pragma unroll
        for (int mi = 0; mi < 4; ++mi)
            #pragma unroll
            for (int r = 0; r < 4; ++r) mx = fmaxf(mx, accs[nt][mi][r]);
        mx = fmaxf(mx, __shfl_xor(mx, 16, 64));
        mx = fmaxf(mx, __shfl_xor(mx, 32, 64));
        float pv[4][4];
        float sum = 0.f;
        #pragma unroll
        for (int mi = 0; mi < 4; ++mi)
            #pragma unroll
            for (int r = 0; r < 4; ++r) {
                float pe = __builtin_amdgcn_exp2f((accs[nt][mi][r] - mx) * LOG2E);
                pv[mi][r] = pe; sum += pe;
            }
        sum += __shfl_xor(sum, 16, 64);
        sum += __shfl_xor(sum, 32, 64);
        float inv = 1.f / sum;
        // attn A-frags: (kk,g,j) -> m = 16*(2kk+(j>>2)) + 4g + (j&3)
        #pragma unroll
        for (int kk = 0; kk < 2; ++kk)
            #pragma unroll
            for (int j = 0; j < 8; ++j)
                afr[nt][kk][j] = (f16)(pv[2 * kk + (j >> 2)][j & 3] * inv);
    }

    // ---- out: 32 c-tiles of 16; B-frags streamed from L2; f32x4 stores ----
    float* ob = out + (size_t)b * CIN * NPIX + nb + 4 * g;
    #pragma unroll 4
    for (int ct = 0; ct < 32; ++ct) {
        int c = 16 * ct + ln;
        f32x4 acc0 = {}, acc1 = {};
        #pragma unroll
        for (int kk = 0; kk < 2; ++kk) {
            f16x8 bfp = *(const f16x8*)(wpv + (((ct * 2 + kk) * 4 + g) * 16 + ln) * 16);
            acc0 = __builtin_amdgcn_mfma_f32_16x16x32_f16(afr[0][kk], bfp, acc0, 0, 0, 0);
            acc1 = __builtin_amdgcn_mfma_f32_16x16x32_f16(afr[1][kk], bfp, acc1, 0, 0, 0);
        }
        *(f32x4*)(ob + (size_t)c * NPIX)      = acc0;
        *(f32x4*)(ob + (size_t)c * NPIX + 16) = acc1;
    }
}

// ---------------------------------------------------------------------------
extern "C" void kernel_launch(void* const* d_in, const int* in_sizes, int n_in,
                              void* d_out, int out_size, void* d_ws, size_t ws_size,
                              hipStream_t stream) {
    (void)in_sizes; (void)n_in; (void)out_size; (void)ws_size;
    const float* x   = (const float*)d_in[0];
    const float* ctx = (const float*)d_in[1];
    const float* Wq  = (const float*)d_in[2];
    const float* Wk  = (const float*)d_in[3];
    const float* Wv  = (const float*)d_in[4];
    const float* Wp  = (const float*)d_in[5];
    float* out = (float*)d_out;
    char* ws = (char*)d_ws;

    prep<<<dim3(4, B_), 1024, 0, stream>>>(ctx, Wk, Wv, Wq, Wp, ws);
    fused<<<dim3(32, B_), 1024, 131072, stream>>>(x, ws, out);
}

// Round 10
// 159.279 us; speedup vs baseline: 1.1927x; 1.1927x over previous
//
#include <hip/hip_runtime.h>
#include <stdint.h>

// Problem constants
#define B_    8
#define CIN   512
#define NPIX  16384
#define CK    256
#define KCTX  64
#define CV    256

typedef _Float16 f16;
typedef _Float16 f16x4 __attribute__((ext_vector_type(4)));
typedef _Float16 f16x8 __attribute__((ext_vector_type(8)));
typedef float    f32x4 __attribute__((ext_vector_type(4)));

#define LOG2E 1.44269504f

// ws layout (bytes), total 1 MB. Both tables in exact MFMA fragment order.
// WQK: A-frag for sim.  byte = ((((s*4+mi)*2+kk)*4+g)*16+ln)*16 + 2*j
//      holds Wqk^T(c,m)*1/16 with c = 64s+32kk+8g+j, m = 16mi+ln
// WPV: B-frag for out.  byte = (((ct*2+kk)*4+g)*16+lnc)*16 + 2*j
//      holds Wpv(c,m) with c = 16ct+lnc, m = 16*(2kk+(j>>2))+4g+(j&3)
#define WQK_OFF 0           // 512 KB : [b][64 KB]
#define WPV_OFF 524288      // 512 KB : [b][64 KB]

#define WAITVM(N) asm volatile("s_waitcnt vmcnt(" #N ")" ::: "memory")
#define LGKM0     asm volatile("s_waitcnt lgkmcnt(0)" ::: "memory")
#define SCHEDB    __builtin_amdgcn_sched_barrier(0)
#define SBAR      __builtin_amdgcn_s_barrier()

__device__ __forceinline__ void gl_lds16(const void* g, void* l) {
    __builtin_amdgcn_global_load_lds(
        (const __attribute__((address_space(1))) uint32_t*)g,
        (__attribute__((address_space(3))) uint32_t*)l, 16, 0, 0);
}

// ---------------------------------------------------------------------------
// prep: grid (4, B), 1024 threads, 64 KB LDS.  (unchanged from rounds 6-9)
// ---------------------------------------------------------------------------
__global__ __launch_bounds__(1024) void prep(const float* __restrict__ ctx,
                                             const float* __restrict__ Wk,
                                             const float* __restrict__ Wv,
                                             const float* __restrict__ Wq,
                                             const float* __restrict__ Wp,
                                             char* __restrict__ ws) {
    __shared__ char lds[65536];
    char* ctx_t = lds;              // 32 KB
    char* kv_s  = lds + 32768;      // 32 KB

    const int p = blockIdx.x;
    const int b = blockIdx.y;
    const int path = p >> 1, h = p & 1;
    const int t = threadIdx.x;
    const int w = t >> 6, l = t & 63, g = l >> 4, ln = l & 15;

    // ---- stage ctx transposed: ctx_t[m][c] f16 swz ----
    {
        const int m4 = (t & 15) * 4, c4 = (t >> 4) * 4;
        const float* cp = ctx + (size_t)b * (CV * KCTX) + (size_t)c4 * KCTX + m4;
        f32x4 xr[4];
        #pragma unroll
        for (int i = 0; i < 4; ++i) xr[i] = *(const f32x4*)(cp + (size_t)i * KCTX);
        #pragma unroll
        for (int j = 0; j < 4; ++j) {
            f16x4 v4; v4[0] = (f16)xr[0][j]; v4[1] = (f16)xr[1][j]; v4[2] = (f16)xr[2][j]; v4[3] = (f16)xr[3][j];
            int m = m4 + j;
            *(f16x4*)(ctx_t + m * 512 + 16 * (((c4 >> 3) & 31) ^ (m & 7)) + 2 * (c4 & 7)) = v4;
        }
    }
    __syncthreads();

    // ---- kv GEMM: D[row][m] = (path? Wv : Wk) * ctx, K=256 ----
    {
        const float* W = path ? Wv : Wk;
        const int rbase = 64 * (w >> 2);
        const int mm = 16 * (w & 3) + ln;
        f32x4 acc[4] = {};
        for (int ks = 0; ks < 8; ++ks) {
            f16x8 bf = *(const f16x8*)(ctx_t + mm * 512 + 16 * ((4 * ks + g) ^ (mm & 7)));
            #pragma unroll
            for (int mi = 0; mi < 4; ++mi) {
                int row = rbase + 16 * mi + ln;
                const float* wp0 = W + (size_t)row * CV + 32 * ks + 8 * g;
                f32x4 lo = *(const f32x4*)wp0, hi = *(const f32x4*)(wp0 + 4);
                f16x8 af;
                #pragma unroll
                for (int j = 0; j < 4; ++j) { af[j] = (f16)lo[j]; af[4 + j] = (f16)hi[j]; }
                acc[mi] = __builtin_amdgcn_mfma_f32_16x16x32_f16(af, bf, acc[mi], 0, 0, 0);
            }
        }
        #pragma unroll
        for (int mi = 0; mi < 4; ++mi)
            #pragma unroll
            for (int r = 0; r < 4; ++r) {
                int row = rbase + 16 * mi + 4 * g + r;
                *(f16*)(kv_s + mm * 512 + 16 * ((((row >> 3) & 31)) ^ (mm & 7)) + 2 * (row & 7)) = (f16)acc[mi][r];
            }
    }
    __syncthreads();

    if (path == 0) {
        // ---- Wqk^T[c][m] = sum_kk Wq[kk][c] k[kk][m]; A gathered from global ----
        f32x4 acc2[4] = {};
        const int cA = 256 * h + 16 * w + ln;
        const float* qcol = Wq + cA;
        for (int ks = 0; ks < 8; ++ks) {
            f16x8 af;
            #pragma unroll
            for (int j = 0; j < 8; ++j)
                af[j] = (f16)qcol[(size_t)(32 * ks + 8 * g + j) * CIN];
            #pragma unroll
            for (int ni = 0; ni < 4; ++ni) {
                int m2 = 16 * ni + ln;
                f16x8 bf = *(const f16x8*)(kv_s + m2 * 512 + 16 * ((4 * ks + g) ^ (m2 & 7)));
                acc2[ni] = __builtin_amdgcn_mfma_f32_16x16x32_f16(af, bf, acc2[ni], 0, 0, 0);
            }
        }
        char* dst = ws + WQK_OFF + b * 65536;
        #pragma unroll
        for (int ni = 0; ni < 4; ++ni)
            #pragma unroll
            for (int r = 0; r < 4; ++r) {
                int c = 256 * h + 16 * w + 4 * g + r;     // k-dim index of sim GEMM
                int s  = c >> 6, kk = (c >> 5) & 1, gk = (c >> 3) & 3, j = c & 7;
                int byte = ((((s * 4 + ni) * 2 + kk) * 4 + gk) * 16 + ln) * 16 + 2 * j;
                *(f16*)(dst + byte) = (f16)(acc2[ni][r] * 0.0625f);   // fold scale 1/16
            }
    } else {
        // ---- Wpv[c][m] = sum_v Wp[c][v] v[v][m]; A direct from global ----
        f32x4 acc2[4] = {};
        const int cA = 256 * h + 16 * w + ln;
        for (int ks = 0; ks < 8; ++ks) {
            const float* pp = Wp + (size_t)cA * CV + 32 * ks + 8 * g;
            f32x4 lo = *(const f32x4*)pp, hi = *(const f32x4*)(pp + 4);
            f16x8 af;
            #pragma unroll
            for (int j = 0; j < 4; ++j) { af[j] = (f16)lo[j]; af[4 + j] = (f16)hi[j]; }
            #pragma unroll
            for (int ni = 0; ni < 4; ++ni) {
                int m2 = 16 * ni + ln;
                f16x8 bf = *(const f16x8*)(kv_s + m2 * 512 + 16 * ((4 * ks + g) ^ (m2 & 7)));
                acc2[ni] = __builtin_amdgcn_mfma_f32_16x16x32_f16(af, bf, acc2[ni], 0, 0, 0);
            }
        }
        char* dst = ws + WPV_OFF + b * 65536;
        #pragma unroll
        for (int ni = 0; ni < 4; ++ni) {
            const int kkm = ni >> 1;
            const int gm  = ln >> 2;
            const int jm  = 4 * (ni & 1) + (ln & 3);
            #pragma unroll
            for (int r = 0; r < 4; ++r) {
                int c = 256 * h + 16 * w + 4 * g + r;     // output-channel index
                int ct = c >> 4, lnc = c & 15;
                int byte = (((ct * 2 + kkm) * 4 + gm) * 16 + lnc) * 16 + 2 * jm;
                *(f16*)(dst + byte) = (f16)acc2[ni][r];
            }
        }
    }
}

// ---------------------------------------------------------------------------
// fused: 1024 threads = 16 waves, 256-px tile, 128 KB dynamic LDS.
//  - Wqk table (64 KB frag-order) staged ONCE -> LDS; no table loads in loop.
//  - x double-buffered [256 n][64 c] f16 swz, prefetch depth 4 (regs), ONE
//    barrier per K-chunk, only vmcnt wait = x chunk issued 3 phases earlier.
//  - out: Wpv re-staged over the table region; linear frag-order ds_reads;
//    f32x4 stores.
// ---------------------------------------------------------------------------
__global__ __launch_bounds__(1024) void fused(const float* __restrict__ x,
                                              const char* __restrict__ ws,
                                              float* __restrict__ out) {
    extern __shared__ char lds[];              // 128 KB dynamic
    char* tab_l = lds;                         // 64 KB: Wqk, later Wpv
    char* x_s   = lds + 65536;                 // 2 x 32 KB: [256 n][64 c] f16 swz

    const int b = blockIdx.y;
    const int n0 = blockIdx.x * 256;
    const int t = threadIdx.x;
    const int w = t >> 6, l = t & 63, g = l >> 4, ln = l & 15;
    const int nB = 16 * w + ln;                // wave's MFMA n-row
    const int fnB = (nB ^ (nB >> 3)) & 7;

    const char* wqk_g = ws + WQK_OFF + b * 65536;
    const char* wpv_g = ws + WPV_OFF + b * 65536;
    const float* xb = x + (size_t)b * CIN * NPIX + n0;

    // staging decomposition: thread t -> c-group cg = t>>6 (c = 4cg..4cg+3),
    // n4 = 4*(t&63). 4 f32x4 loads = rows 4cg+i, cols n4..n4+3.
    const int cg = t >> 6;
    const int n4 = 4 * (t & 63);

    f32x4 xr[4][4];   // 4 prefetch slots

#define STAGE_LOAD(S, SLOT)                                                    \
    {                                                                          \
        const float* xp = xb + (size_t)(64 * (S) + 4 * cg) * NPIX + n4;        \
        _Pragma("unroll")                                                      \
        for (int i = 0; i < 4; ++i)                                            \
            xr[SLOT][i] = *(const f32x4*)(xp + (size_t)i * NPIX);              \
    }

#define STAGE_WRITE(BUF, SLOT)                                                 \
    {                                                                          \
        _Pragma("unroll")                                                      \
        for (int j = 0; j < 4; ++j) {                                          \
            f16x4 v4;                                                          \
            v4[0] = (f16)xr[SLOT][0][j]; v4[1] = (f16)xr[SLOT][1][j];          \
            v4[2] = (f16)xr[SLOT][2][j]; v4[3] = (f16)xr[SLOT][3][j];          \
            int nl = n4 + j;                                                   \
            int fn = (nl ^ (nl >> 3)) & 7;                                     \
            *(f16x4*)((BUF) + nl * 128 + 16 * ((cg >> 1) ^ fn) + 8 * (cg & 1)) = v4; \
        }                                                                      \
    }

    // ---- prologue: stage Wqk table (4 ops) + x0..x3 (16 ops) ----
    #pragma unroll
    for (int r = 0; r < 4; ++r) {
        int ch = t + 1024 * r;
        gl_lds16(wqk_g + ch * 16, tab_l + ch * 16);
    }
    SCHEDB;
    STAGE_LOAD(0, 0); SCHEDB;
    STAGE_LOAD(1, 1); SCHEDB;
    STAGE_LOAD(2, 2); SCHEDB;
    STAGE_LOAD(3, 3); SCHEDB;
    WAITVM(12);   // retire wqk-stage + x0; x1..x3 in flight
    SCHEDB;
    STAGE_WRITE(x_s, 0);
    LGKM0; SCHEDB; SBAR; SCHEDB;

    // ---- sim: 8 c-chunks; ONE barrier/iter; only wait = 3-phase-old x ----
    f32x4 accs[4] = {};   // D[m 64][n 16]: acc[mi], m = 16mi + 4g + r
    #pragma unroll
    for (int s = 0; s < 8; ++s) {
        const char* xc = x_s + (s & 1) * 32768;
        #pragma unroll
        for (int kk = 0; kk < 2; ++kk) {
            f16x8 bf = *(const f16x8*)(xc + nB * 128 + 16 * ((4 * kk + g) ^ fnB));
            #pragma unroll
            for (int mi = 0; mi < 4; ++mi) {
                f16x8 af = *(const f16x8*)(tab_l + ((((s * 4 + mi) * 2 + kk) * 4 + g) * 16 + ln) * 16);
                accs[mi] = __builtin_amdgcn_mfma_f32_16x16x32_f16(af, bf, accs[mi], 0, 0, 0);
            }
        }
        SCHEDB;
        if (s < 7) {
            if (s < 4) { STAGE_LOAD(s + 4, (s & 3)); SCHEDB; }
            // retire x(s+1): newer = chunks {s+2..min(s+4,7)}
            if (s < 4)      { WAITVM(12); }
            else if (s == 4){ WAITVM(8); }
            else if (s == 5){ WAITVM(4); }
            else            { WAITVM(0); }
            SCHEDB;
            STAGE_WRITE(x_s + ((s + 1) & 1) * 32768, ((s + 1) & 3));
            LGKM0;
        } else {
            LGKM0;   // my table/x reads done (data consumed by MFMA anyway)
        }
        SCHEDB; SBAR; SCHEDB;
    }

    // ---- stage Wpv over the table region (all reads of wqk are behind SBAR) ----
    #pragma unroll
    for (int r = 0; r < 4; ++r) {
        int ch = t + 1024 * r;
        gl_lds16(wpv_g + ch * 16, tab_l + ch * 16);
    }

    // ---- softmax over m (64), in-register (overlaps wpv staging) ----
    float mx = accs[0][0];
    #pragma unroll
    for (int mi = 0; mi < 4; ++mi)
        #pragma unroll
        for (int r = 0; r < 4; ++r) mx = fmaxf(mx, accs[mi][r]);
    mx = fmaxf(mx, __shfl_xor(mx, 16, 64));
    mx = fmaxf(mx, __shfl_xor(mx, 32, 64));
    float pv[4][4];
    float sum = 0.f;
    #pragma unroll
    for (int mi = 0; mi < 4; ++mi)
        #pragma unroll
        for (int r = 0; r < 4; ++r) {
            float pe = __builtin_amdgcn_exp2f((accs[mi][r] - mx) * LOG2E);
            pv[mi][r] = pe; sum += pe;
        }
    sum += __shfl_xor(sum, 16, 64);
    sum += __shfl_xor(sum, 32, 64);
    float inv = 1.f / sum;

    // attn A-frags: (kk,g,j) -> m = 16*(2kk+(j>>2)) + 4g + (j&3)
    f16x8 afr[2];
    #pragma unroll
    for (int kk = 0; kk < 2; ++kk)
        #pragma unroll
        for (int j = 0; j < 8; ++j)
            afr[kk][j] = (f16)(pv[2 * kk + (j >> 2)][j & 3] * inv);

    WAITVM(0); SCHEDB; SBAR; SCHEDB;   // Wpv staged for all waves

    // ---- out: 32 c-tiles of 16; linear frag-order ds_reads; f32x4 stores ----
    float* ob = out + (size_t)b * CIN * NPIX + n0 + 16 * w + 4 * g;
    #pragma unroll 4
    for (int ct = 0; ct < 32; ++ct) {
        int c = 16 * ct + ln;
        f32x4 acc = {};
        #pragma unroll
        for (int kk = 0; kk < 2; ++kk) {
            f16x8 bfp = *(const f16x8*)(tab_l + (((ct * 2 + kk) * 4 + g) * 16 + ln) * 16);
            acc = __builtin_amdgcn_mfma_f32_16x16x32_f16(afr[kk], bfp, acc, 0, 0, 0);
        }
        *(f32x4*)(ob + (size_t)c * NPIX) = acc;
    }
}

// ---------------------------------------------------------------------------
extern "C" void kernel_launch(void* const* d_in, const int* in_sizes, int n_in,
                              void* d_out, int out_size, void* d_ws, size_t ws_size,
                              hipStream_t stream) {
    (void)in_sizes; (void)n_in; (void)out_size; (void)ws_size;
    const float* x   = (const float*)d_in[0];
    const float* ctx = (const float*)d_in[1];
    const float* Wq  = (const float*)d_in[2];
    const float* Wk  = (const float*)d_in[3];
    const float* Wv  = (const float*)d_in[4];
    const float* Wp  = (const float*)d_in[5];
    float* out = (float*)d_out;
    char* ws = (char*)d_ws;

    prep<<<dim3(4, B_), 1024, 0, stream>>>(ctx, Wk, Wv, Wq, Wp, ws);
    fused<<<dim3(NPIX / 256, B_), 1024, 131072, stream>>>(x, ws, out);
}